// Round 5
// baseline (491.707 us; speedup 1.0000x reference)
//
#include <hip/hip_runtime.h>
#include <hip/hip_bf16.h>
#include <stdint.h>

#define NH 16
#define DR 64
#define DC 512
#define DV 128
#define DN 128
#define DQH 192
#define HDIM 2048
#define KVL 4096
#define BSZ 32

typedef __attribute__((ext_vector_type(8))) short bf16x8;
typedef __attribute__((ext_vector_type(4))) float f32x4;
typedef __attribute__((ext_vector_type(4))) unsigned short u16x4;
typedef __attribute__((ext_vector_type(8))) unsigned short u16x8;

#define MFMA16(a, b, c) __builtin_amdgcn_mfma_f32_16x16x32_bf16(a, b, c, 0, 0, 0)

constexpr float SCALE_F = 0.07216878364870323f;  // 192^-0.5
constexpr float EPS_F = 1e-6f;
constexpr float NEG_BIG = -1e30f;

__device__ __forceinline__ unsigned short f2bf(float f) {
  __hip_bfloat16 h = __float2bfloat16(f);
  return __builtin_bit_cast(unsigned short, h);
}

// ---------------------------------------------------------------------------
// Skinny GEMM: out[32][N] = A[32][K] @ W[K][N], bf16 MFMA, fp32 accum.
// Staging is register-batched (issue all 12 float4 loads, fence, then
// convert+ds_write) -> one HBM latency per iteration, not per load.
// ---------------------------------------------------------------------------
__global__ __launch_bounds__(256) void k_skinny(
    const float* __restrict__ A, const float* __restrict__ W,
    float* __restrict__ out, const int K, const int N) {
  const int n0 = blockIdx.x * 16;
  const int t = threadIdx.x;
  const int w = t >> 6, l = t & 63;
  const int lr = l & 15, lg = l >> 4;

  __shared__ unsigned short lA[4][32][72];
  __shared__ unsigned short lB[4][16][72];
  __shared__ float lC[4][2][16][16];

  f32x4 acc0 = {0.f, 0.f, 0.f, 0.f};
  f32x4 acc1 = {0.f, 0.f, 0.f, 0.f};

  const int bb = l >> 1;
  const int half = (l & 1) << 5;
  const int wk = l >> 2;
  const int wn = (l & 3) * 4;

  const int nch = K >> 6;
  for (int kc = w; kc < nch; kc += 4) {
    const int k0 = kc << 6;
    // ---- issue the full load batch ----
    float4 av[8];
    const float* ap = A + (long)bb * K + k0 + half;
    #pragma unroll
    for (int i = 0; i < 8; ++i) av[i] = *(const float4*)(ap + i * 4);
    float4 wv[4];
    #pragma unroll
    for (int p = 0; p < 4; ++p)
      wv[p] = *(const float4*)(W + (long)(k0 + p * 16 + wk) * N + n0 + wn);
    __builtin_amdgcn_sched_barrier(0);
    // ---- convert + LDS write ----
    #pragma unroll
    for (int i = 0; i < 8; ++i) {
      u16x4 u = {f2bf(av[i].x), f2bf(av[i].y), f2bf(av[i].z), f2bf(av[i].w)};
      *(u16x4*)&lA[w][bb][half + i * 4] = u;
    }
    #pragma unroll
    for (int p = 0; p < 4; ++p) {
      const int k = p * 16 + wk;
      lB[w][wn + 0][k] = f2bf(wv[p].x);
      lB[w][wn + 1][k] = f2bf(wv[p].y);
      lB[w][wn + 2][k] = f2bf(wv[p].z);
      lB[w][wn + 3][k] = f2bf(wv[p].w);
    }
    #pragma unroll
    for (int ks = 0; ks < 2; ++ks) {
      const int ko = ks * 32 + lg * 8;
      const bf16x8 bfr = *(const bf16x8*)&lB[w][lr][ko];
      const bf16x8 a0 = *(const bf16x8*)&lA[w][lr][ko];
      const bf16x8 a1 = *(const bf16x8*)&lA[w][16 + lr][ko];
      acc0 = MFMA16(a0, bfr, acc0);
      acc1 = MFMA16(a1, bfr, acc1);
    }
  }
  #pragma unroll
  for (int r = 0; r < 4; ++r) {
    lC[w][0][lg * 4 + r][lr] = acc0[r];
    lC[w][1][lg * 4 + r][lr] = acc1[r];
  }
  __syncthreads();
  for (int i = t; i < 512; i += 256) {
    const int mt = i >> 8, bi = (i >> 4) & 15, n = i & 15;
    const float s = lC[0][mt][bi][n] + lC[1][mt][bi][n] +
                    lC[2][mt][bi][n] + lC[3][mt][bi][n];
    out[(long)(mt * 16 + bi) * N + n0 + n] = s;
  }
}

// ---------------------------------------------------------------------------
// K2: RMSNorm + RoPE. Writes the new ckv/kpe rows DIRECTLY into the caches
// (inputs restored before every timed launch -> idempotent).
// ---------------------------------------------------------------------------
__global__ __launch_bounds__(256) void k2_normrope(
    const float* __restrict__ latent, const float* __restrict__ q_ws,
    const float* __restrict__ lnw, const float* __restrict__ cosv,
    const float* __restrict__ sinv, float* __restrict__ ckv_mut,
    float* __restrict__ kpe_mut, float* __restrict__ qpe_ws) {
  const int b = blockIdx.x, t = threadIdx.x;
  __shared__ float red[4];
  const float x0 = latent[b * 576 + t * 2];
  const float x1 = latent[b * 576 + t * 2 + 1];
  float ss = x0 * x0 + x1 * x1;
  #pragma unroll
  for (int m = 1; m < 64; m <<= 1) ss += __shfl_xor(ss, m);
  if ((t & 63) == 0) red[t >> 6] = ss;
  __syncthreads();
  const float var = (red[0] + red[1] + red[2] + red[3]) * (1.f / 512.f);
  const float rstd = rsqrtf(var + EPS_F);
  float* crow = ckv_mut + ((long)b * KVL + (KVL - 1)) * DC;
  crow[t * 2] = x0 * rstd * lnw[t * 2];
  crow[t * 2 + 1] = x1 * rstd * lnw[t * 2 + 1];
  if (t < 64) {
    const float xr = latent[b * 576 + 512 + t];
    const float rot = (t < 32) ? -latent[b * 576 + 512 + t + 32]
                               : latent[b * 576 + 512 + t - 32];
    kpe_mut[((long)b * KVL + (KVL - 1)) * DR + t] = xr * cosv[t] + rot * sinv[t];
  }
  for (int i = t; i < NH * 64; i += 256) {
    const int hh = i >> 6, r = i & 63;
    const float xr = q_ws[b * 3072 + hh * DQH + 128 + r];
    const float rot = (r < 32) ? -q_ws[b * 3072 + hh * DQH + 128 + r + 32]
                               : q_ws[b * 3072 + hh * DQH + 128 + r - 32];
    qpe_ws[(b * NH + hh) * 64 + r] = (xr * cosv[r] + rot * sinv[r]) * SCALE_F;
  }
}

// ---------------------------------------------------------------------------
// K3: q_nope2[b,h,c] = sum_d q_nope[b,h,d] * W_UK[h,c,d], output * SCALE.
// Staging register-batched (4 + 16 float4 in flight).
// ---------------------------------------------------------------------------
__global__ __launch_bounds__(256) void k3_absorb(
    const float* __restrict__ q_ws, const float* __restrict__ Wuk,
    float* __restrict__ qn2_ws) {
  const int h = blockIdx.x >> 2, ct = blockIdx.x & 3;
  const int c0 = ct * 128;
  const int t = threadIdx.x, w = t >> 6, l = t & 63;
  const int lr = l & 15, lg = l >> 4;
  __shared__ unsigned short lA[32][136];
  __shared__ unsigned short lB[128][136];
  {
    // ---- issue batch: A (4) + B (16) ----
    const int ab = t >> 3, ad0 = (t & 7) * 16;
    float4 avv[4];
    #pragma unroll
    for (int i = 0; i < 4; ++i)
      avv[i] = *(const float4*)(q_ws + (long)ab * 3072 + h * DQH + ad0 + i * 4);
    const int c = t >> 1, d0 = (t & 1) * 64;
    float4 bvv[16];
    #pragma unroll
    for (int i = 0; i < 16; ++i)
      bvv[i] = *(const float4*)(Wuk + ((long)h * 512 + c0 + c) * 128 + d0 + i * 4);
    __builtin_amdgcn_sched_barrier(0);
    #pragma unroll
    for (int i = 0; i < 4; ++i) {
      u16x4 u = {f2bf(avv[i].x), f2bf(avv[i].y), f2bf(avv[i].z), f2bf(avv[i].w)};
      *(u16x4*)&lA[ab][ad0 + i * 4] = u;
    }
    #pragma unroll
    for (int i = 0; i < 16; ++i) {
      u16x4 u = {f2bf(bvv[i].x), f2bf(bvv[i].y), f2bf(bvv[i].z), f2bf(bvv[i].w)};
      *(u16x4*)&lB[c][d0 + i * 4] = u;
    }
  }
  __syncthreads();
  f32x4 acc[2][2];
  #pragma unroll
  for (int mt = 0; mt < 2; ++mt)
    #pragma unroll
    for (int nt = 0; nt < 2; ++nt) acc[mt][nt] = (f32x4){0.f, 0.f, 0.f, 0.f};
  #pragma unroll
  for (int nt = 0; nt < 2; ++nt) {
    const int cc = w * 32 + nt * 16 + lr;
    #pragma unroll
    for (int ks = 0; ks < 4; ++ks) {
      const int ko = ks * 32 + lg * 8;
      const bf16x8 bfr = *(const bf16x8*)&lB[cc][ko];
      const bf16x8 a0 = *(const bf16x8*)&lA[lr][ko];
      const bf16x8 a1 = *(const bf16x8*)&lA[16 + lr][ko];
      acc[0][nt] = MFMA16(a0, bfr, acc[0][nt]);
      acc[1][nt] = MFMA16(a1, bfr, acc[1][nt]);
    }
  }
  #pragma unroll
  for (int mt = 0; mt < 2; ++mt)
    #pragma unroll
    for (int nt = 0; nt < 2; ++nt)
      #pragma unroll
      for (int r = 0; r < 4; ++r) {
        const int bb = mt * 16 + lg * 4 + r;
        const int c = c0 + w * 32 + nt * 16 + lr;
        qn2_ws[((long)bb * NH + h) * 512 + c] = acc[mt][nt][r] * SCALE_F;
      }
}

// ---------------------------------------------------------------------------
// K4: flash-decode attention (register-batched staging, verified r3).
// ---------------------------------------------------------------------------
__global__ __launch_bounds__(256, 2) void k4_attn(
    const float* __restrict__ ckv, const float* __restrict__ kpe,
    const float* __restrict__ qn2, const float* __restrict__ qpe,
    float* __restrict__ pacc, float* __restrict__ pml) {
  const int b = blockIdx.x >> 4, ch = blockIdx.x & 15;
  const int t = threadIdx.x, w = t >> 6, l = t & 63;
  const int lr = l & 15, lg = l >> 4;

  __shared__ unsigned short ct_[16 * 2056];  // ckv tile 64x512 bf16 subtiled
  __shared__ unsigned short pt_[16 * 264];   // kpe tile 64x64 bf16 subtiled
  __shared__ unsigned short p_lds[16 * 72];  // probs bf16 [h][72]
  __shared__ float wred[2][4][16];           // cross-wave max/sum

  bf16x8 qa[18];
  {
    const float* qb = qn2 + ((long)b * NH + lr) * 512;
    #pragma unroll
    for (int s = 0; s < 16; ++s) {
      const float4 v0 = *(const float4*)(qb + s * 32 + lg * 8);
      const float4 v1 = *(const float4*)(qb + s * 32 + lg * 8 + 4);
      bf16x8 f;
      f[0] = (short)f2bf(v0.x); f[1] = (short)f2bf(v0.y);
      f[2] = (short)f2bf(v0.z); f[3] = (short)f2bf(v0.w);
      f[4] = (short)f2bf(v1.x); f[5] = (short)f2bf(v1.y);
      f[6] = (short)f2bf(v1.z); f[7] = (short)f2bf(v1.w);
      qa[s] = f;
    }
    const float* qp = qpe + ((long)b * NH + lr) * 64;
    #pragma unroll
    for (int s = 0; s < 2; ++s) {
      const float4 v0 = *(const float4*)(qp + s * 32 + lg * 8);
      const float4 v1 = *(const float4*)(qp + s * 32 + lg * 8 + 4);
      bf16x8 f;
      f[0] = (short)f2bf(v0.x); f[1] = (short)f2bf(v0.y);
      f[2] = (short)f2bf(v0.z); f[3] = (short)f2bf(v0.w);
      f[4] = (short)f2bf(v1.x); f[5] = (short)f2bf(v1.y);
      f[6] = (short)f2bf(v1.z); f[7] = (short)f2bf(v1.w);
      qa[16 + s] = f;
    }
  }

  f32x4 acc[8];
  #pragma unroll
  for (int i = 0; i < 8; ++i) acc[i] = (f32x4){0.f, 0.f, 0.f, 0.f};
  float m_run[4] = {NEG_BIG, NEG_BIG, NEG_BIG, NEG_BIG};
  float l_run[4] = {0.f, 0.f, 0.f, 0.f};

  for (int st = 0; st < 4; ++st) {
    const int kbase = ch * 256 + st * 64;
    const float* cbase = ckv + ((long)b * KVL + kbase) * DC;
    const float* pbase = kpe + ((long)b * KVL + kbase) * DR;

    float4 tkp[4];
    #pragma unroll
    for (int j = 0; j < 4; ++j)
      tkp[j] = *(const float4*)(pbase + j * 1024 + t * 4);
    float4 ta[16];
    #pragma unroll
    for (int j = 0; j < 16; ++j)
      ta[j] = *(const float4*)(cbase + j * 1024 + t * 4);
    __builtin_amdgcn_sched_barrier(0);
    #pragma unroll
    for (int j = 0; j < 4; ++j) {
      const int f = j * 1024 + t * 4;
      const int kk = f >> 6, r = f & 63;
      u16x4 u = {f2bf(tkp[j].x), f2bf(tkp[j].y), f2bf(tkp[j].z), f2bf(tkp[j].w)};
      *(u16x4*)&pt_[(kk >> 2) * 264 + (r >> 4) * 64 + (kk & 3) * 16 + (r & 15)] = u;
    }
    #pragma unroll
    for (int j = 0; j < 16; ++j) {
      const int f = j * 1024 + t * 4;
      const int kk = f >> 9, c = f & 511;
      u16x4 u = {f2bf(ta[j].x), f2bf(ta[j].y), f2bf(ta[j].z), f2bf(ta[j].w)};
      *(u16x4*)&ct_[(kk >> 2) * 2056 + (c >> 4) * 64 + (kk & 3) * 16 + (c & 15)] = u;
    }
    float4 tb[16];
    #pragma unroll
    for (int j = 0; j < 16; ++j)
      tb[j] = *(const float4*)(cbase + 16384 + j * 1024 + t * 4);
    __builtin_amdgcn_sched_barrier(0);
    #pragma unroll
    for (int j = 0; j < 16; ++j) {
      const int f = 16384 + j * 1024 + t * 4;
      const int kk = f >> 9, c = f & 511;
      u16x4 u = {f2bf(tb[j].x), f2bf(tb[j].y), f2bf(tb[j].z), f2bf(tb[j].w)};
      *(u16x4*)&ct_[(kk >> 2) * 2056 + (c >> 4) * 64 + (kk & 3) * 16 + (c & 15)] = u;
    }
    __syncthreads();  // B1

    f32x4 s4 = {0.f, 0.f, 0.f, 0.f};
    {
      const int kk = w * 16 + lr;
      const int cbase_l = (kk >> 2) * 2056 + (kk & 3) * 16;
      const int coff = (lg >> 1) * 64 + (lg & 1) * 8;
      #pragma unroll
      for (int s = 0; s < 16; ++s) {
        const bf16x8 bfr = *(const bf16x8*)&ct_[cbase_l + coff + s * 128];
        s4 = MFMA16(qa[s], bfr, s4);
      }
      const int pbase_l = (kk >> 2) * 264 + (kk & 3) * 16 + coff;
      #pragma unroll
      for (int s = 0; s < 2; ++s) {
        const bf16x8 bfr = *(const bf16x8*)&pt_[pbase_l + s * 128];
        s4 = MFMA16(qa[16 + s], bfr, s4);
      }
    }

    float pm[4];
    #pragma unroll
    for (int r = 0; r < 4; ++r) {
      float v = s4[r];
      v = fmaxf(v, __shfl_xor(v, 1));
      v = fmaxf(v, __shfl_xor(v, 2));
      v = fmaxf(v, __shfl_xor(v, 4));
      v = fmaxf(v, __shfl_xor(v, 8));
      pm[r] = v;
    }
    if (lr == 0) {
      #pragma unroll
      for (int r = 0; r < 4; ++r) wred[0][w][lg * 4 + r] = pm[r];
    }
    __syncthreads();  // B2

    float al[4], p4[4], ps[4];
    #pragma unroll
    for (int r = 0; r < 4; ++r) {
      const int hh = lg * 4 + r;
      float mn = fmaxf(fmaxf(wred[0][0][hh], wred[0][1][hh]),
                       fmaxf(wred[0][2][hh], wred[0][3][hh]));
      mn = fmaxf(mn, m_run[r]);
      al[r] = __expf(m_run[r] - mn);
      m_run[r] = mn;
      p4[r] = __expf(s4[r] - mn);
      float sv = p4[r];
      sv += __shfl_xor(sv, 1);
      sv += __shfl_xor(sv, 2);
      sv += __shfl_xor(sv, 4);
      sv += __shfl_xor(sv, 8);
      ps[r] = sv;
    }
    #pragma unroll
    for (int nt = 0; nt < 8; ++nt)
      #pragma unroll
      for (int r = 0; r < 4; ++r) acc[nt][r] *= al[r];
    #pragma unroll
    for (int r = 0; r < 4; ++r)
      p_lds[(lg * 4 + r) * 72 + w * 16 + lr] = f2bf(p4[r]);
    if (lr == 0) {
      #pragma unroll
      for (int r = 0; r < 4; ++r) wred[1][w][lg * 4 + r] = ps[r];
    }
    __syncthreads();  // B3

    #pragma unroll
    for (int r = 0; r < 4; ++r) {
      const int hh = lg * 4 + r;
      l_run[r] = l_run[r] * al[r] + (wred[1][0][hh] + wred[1][1][hh] +
                                     wred[1][2][hh] + wred[1][3][hh]);
    }

    #pragma unroll
    for (int ks = 0; ks < 2; ++ks) {
      const bf16x8 pa = *(const bf16x8*)&p_lds[lr * 72 + ks * 32 + lg * 8];
      const int kg0 = (ks * 32 + lg * 8) >> 2;
      #pragma unroll
      for (int nt = 0; nt < 8; ++nt) {
        const int c = w * 128 + nt * 16 + lr;
        const int a0 = kg0 * 2056 + (c >> 4) * 64 + (c & 15);
        bf16x8 bfr;
        bfr[0] = (short)ct_[a0];
        bfr[1] = (short)ct_[a0 + 16];
        bfr[2] = (short)ct_[a0 + 32];
        bfr[3] = (short)ct_[a0 + 48];
        bfr[4] = (short)ct_[a0 + 2056];
        bfr[5] = (short)ct_[a0 + 2056 + 16];
        bfr[6] = (short)ct_[a0 + 2056 + 32];
        bfr[7] = (short)ct_[a0 + 2056 + 48];
        acc[nt] = MFMA16(pa, bfr, acc[nt]);
      }
    }
    __syncthreads();  // B4
  }

  #pragma unroll
  for (int nt = 0; nt < 8; ++nt)
    #pragma unroll
    for (int r = 0; r < 4; ++r) {
      const int hh = lg * 4 + r;
      const int c = w * 128 + nt * 16 + lr;
      pacc[(((long)b * 16 + ch) * NH + hh) * 512 + c] = acc[nt][r];
    }
  if (w == 0 && lr == 0) {
    #pragma unroll
    for (int r = 0; r < 4; ++r) {
      const int hh = lg * 4 + r;
      pml[(((long)b * 16 + ch) * NH + hh) * 2 + 0] = m_run[r];
      pml[(((long)b * 16 + ch) * NH + hh) * 2 + 1] = l_run[r];
    }
  }
}

// ---------------------------------------------------------------------------
// K5a: combine 16 chunk-partials -> normalized attn (bf16). grid 512 = (b,h).
// ---------------------------------------------------------------------------
__global__ __launch_bounds__(256) void k5a_combine(
    const float* __restrict__ pacc, const float* __restrict__ pml,
    unsigned short* __restrict__ attn_g) {
  const int bh = blockIdx.x, b = bh >> 4, h = bh & 15;
  const int t = threadIdx.x;
  __shared__ float sm[16], sl[16];
  if (t < 16) {
    sm[t] = pml[(((long)b * 16 + t) * NH + h) * 2 + 0];
    sl[t] = pml[(((long)b * 16 + t) * NH + h) * 2 + 1];
  }
  __syncthreads();
  float M = NEG_BIG;
  #pragma unroll
  for (int c = 0; c < 16; ++c) M = fmaxf(M, sm[c]);
  float wgt[16];
  float L = 0.f;
  #pragma unroll
  for (int c = 0; c < 16; ++c) {
    wgt[c] = __expf(sm[c] - M);
    L += sl[c] * wgt[c];
  }
  const float invL = 1.f / L;
  const int c0 = t * 2;
  float a0 = 0.f, a1 = 0.f;
  #pragma unroll
  for (int cch = 0; cch < 16; ++cch) {
    const float2 v =
        *(const float2*)&pacc[(((long)b * 16 + cch) * NH + h) * 512 + c0];
    a0 += v.x * wgt[cch];
    a1 += v.y * wgt[cch];
  }
  const unsigned int pack =
      (unsigned int)f2bf(a0 * invL) | ((unsigned int)f2bf(a1 * invL) << 16);
  *(unsigned int*)&attn_g[((long)b * NH + h) * 512 + c0] = pack;
}

// ---------------------------------------------------------------------------
// K5b: out_ws[b, h*128+v] = attn[b,h,:] @ W_UV[h,:,v].  grid 32 = (h, vtile).
// Staging register-batched: att (8 u16x8) + Wuv (2 batches of 16 float4).
// ---------------------------------------------------------------------------
__global__ __launch_bounds__(256) void k5b_uv(
    const unsigned short* __restrict__ attn_g, const float* __restrict__ Wuv,
    float* __restrict__ out_ws) {
  const int h = blockIdx.x >> 1, vt = blockIdx.x & 1;
  const int t = threadIdx.x, w = t >> 6, l = t & 63;
  const int lr = l & 15, lg = l >> 4;
  __shared__ unsigned short att[32][520];
  __shared__ unsigned short Wt[64][520];
  const int ab = t >> 3, acol0 = (t & 7) * 64;
  const int wc = t >> 4, wv4 = (t & 15) * 4;
  {
    u16x8 avv[8];
    const unsigned short* src = attn_g + ((long)ab * NH + h) * 512 + acol0;
    #pragma unroll
    for (int j = 0; j < 8; ++j) avv[j] = *(const u16x8*)(src + j * 8);
    float4 wvv[16];
    #pragma unroll
    for (int rep = 0; rep < 16; ++rep)
      wvv[rep] = *(const float4*)(Wuv + ((long)h * 512 + rep * 16 + wc) * 128 +
                                  vt * 64 + wv4);
    __builtin_amdgcn_sched_barrier(0);
    #pragma unroll
    for (int j = 0; j < 8; ++j) *(u16x8*)&att[ab][acol0 + j * 8] = avv[j];
    #pragma unroll
    for (int rep = 0; rep < 16; ++rep) {
      const int c = rep * 16 + wc;
      Wt[wv4 + 0][c] = f2bf(wvv[rep].x);
      Wt[wv4 + 1][c] = f2bf(wvv[rep].y);
      Wt[wv4 + 2][c] = f2bf(wvv[rep].z);
      Wt[wv4 + 3][c] = f2bf(wvv[rep].w);
    }
    float4 wvv2[16];
    #pragma unroll
    for (int rep = 0; rep < 16; ++rep)
      wvv2[rep] = *(const float4*)(Wuv + ((long)h * 512 + 256 + rep * 16 + wc) * 128 +
                                   vt * 64 + wv4);
    __builtin_amdgcn_sched_barrier(0);
    #pragma unroll
    for (int rep = 0; rep < 16; ++rep) {
      const int c = 256 + rep * 16 + wc;
      Wt[wv4 + 0][c] = f2bf(wvv2[rep].x);
      Wt[wv4 + 1][c] = f2bf(wvv2[rep].y);
      Wt[wv4 + 2][c] = f2bf(wvv2[rep].z);
      Wt[wv4 + 3][c] = f2bf(wvv2[rep].w);
    }
  }
  __syncthreads();
  f32x4 acc0 = {0.f, 0.f, 0.f, 0.f};
  f32x4 acc1 = {0.f, 0.f, 0.f, 0.f};
  #pragma unroll
  for (int ks = 0; ks < 16; ++ks) {
    const int ko = ks * 32 + lg * 8;
    const bf16x8 bfr = *(const bf16x8*)&Wt[w * 16 + lr][ko];
    const bf16x8 a0 = *(const bf16x8*)&att[lr][ko];
    const bf16x8 a1 = *(const bf16x8*)&att[16 + lr][ko];
    acc0 = MFMA16(a0, bfr, acc0);
    acc1 = MFMA16(a1, bfr, acc1);
  }
  #pragma unroll
  for (int r = 0; r < 4; ++r) {
    const int v = h * 128 + vt * 64 + w * 16 + lr;
    out_ws[(long)(lg * 4 + r) * 2048 + v] = acc0[r];
    out_ws[(long)(16 + lg * 4 + r) * 2048 + v] = acc1[r];
  }
}

// ---------------------------------------------------------------------------
extern "C" void kernel_launch(void* const* d_in, const int* in_sizes, int n_in,
                              void* d_out, int out_size, void* d_ws,
                              size_t ws_size, hipStream_t stream) {
  const float* hidden = (const float*)d_in[0];
  float* ckv = (float*)d_in[1];   // mutated: row 4095 overwritten (restored
  float* kpec = (float*)d_in[2];  // by harness before every launch)
  const float* Wuqr = (const float*)d_in[3];
  const float* Wkva = (const float*)d_in[4];
  const float* lnw = (const float*)d_in[5];
  const float* Wuk = (const float*)d_in[6];
  const float* Wuv = (const float*)d_in[7];
  const float* Wo = (const float*)d_in[8];
  const float* cosv = (const float*)d_in[9];
  const float* sinv = (const float*)d_in[10];
  float* out = (float*)d_out;

  float* ws = (float*)d_ws;
  float* q_ws = ws;                      // 32*3072
  float* latent_ws = q_ws + 98304;       // 32*576
  float* qn2_ws = latent_ws + 18432;     // 32*16*512
  float* qpe_ws = qn2_ws + 262144;       // 32*16*64
  float* pacc = qpe_ws + 32768;          // 32*16*16*512
  float* pml = pacc + 4194304;           // 32*16*16*2
  unsigned short* attn_g = (unsigned short*)(pml + 16384);  // 32*16*512 u16
  float* out_ws = pml + 16384 + 131072;  // 32*2048

  k_skinny<<<192, 256, 0, stream>>>(hidden, Wuqr, q_ws, 2048, 3072);
  k_skinny<<<36, 256, 0, stream>>>(hidden, Wkva, latent_ws, 2048, 576);
  k2_normrope<<<32, 256, 0, stream>>>(latent_ws, q_ws, lnw, cosv, sinv, ckv,
                                      kpec, qpe_ws);
  k3_absorb<<<64, 256, 0, stream>>>(q_ws, Wuk, qn2_ws);
  k4_attn<<<512, 256, 0, stream>>>(ckv, kpec, qn2_ws, qpe_ws, pacc, pml);
  k5a_combine<<<512, 256, 0, stream>>>(pacc, pml, attn_g);
  k5b_uv<<<32, 256, 0, stream>>>(attn_g, Wuv, out_ws);
  k_skinny<<<128, 256, 0, stream>>>(out_ws, Wo, out, 2048, 2048);
}